// Round 7
// baseline (339.862 us; speedup 1.0000x reference)
//
#include <hip/hip_runtime.h>
#include <stdint.h>

typedef unsigned int uint32;
typedef unsigned long long u64;
typedef unsigned short u16;
typedef short short8 __attribute__((ext_vector_type(8)));
typedef float floatx4 __attribute__((ext_vector_type(4)));

// ---------------- workspace layout (bytes) ----------------
#define OFF_S      0u           // s[16][512] f32        : 32768
#define OFF_DS     32768u       // dscale[16][512] f32   : 32768
#define OFF_WSUM   65536u       // wsum[512][512] f32    : 1 MB
#define OFF_WPACK  1114112u     // wpack[9][512][512] bf16 (m=tap*512+oc, k=ic): 4.5 MB
#define OFF_XST    5832704u     // xst[16*1024][512] bf16 (n=b*1024+px, k=ic): 16 MB
#define OFF_U      22609920u    // U[4608][NB*1024] bf16 : NB*9.44 MB

__device__ __forceinline__ u16 f2bf(float x){
    uint32 u = __float_as_uint(x);
    uint32 r = (u + 0x7FFFu + ((u>>16)&1u)) >> 16;
    return (u16)r;
}
__device__ __forceinline__ float bf2f(u16 h){
    return __uint_as_float(((uint32)h)<<16);
}

#define GLL16(gp, lp) \
    __builtin_amdgcn_global_load_lds( \
        (const __attribute__((address_space(1))) void*)(gp), \
        (__attribute__((address_space(3))) void*)(lp), 16, 0, 0)

// ---- s[b][ic] = style[b]·mod_weight[ic] * mod_scale + mod_bias[ic] ----
__global__ __launch_bounds__(256) void k_style(const float* __restrict__ style,
                                               const float* __restrict__ mw,
                                               const float* __restrict__ mb,
                                               float* __restrict__ s){
    int gid = blockIdx.x*4 + (threadIdx.x>>6);
    int lane = threadIdx.x & 63;
    int b = gid>>9, ic = gid & 511;
    const float* sp = style + b*512;
    const float* wp = mw + (size_t)ic*512;
    float acc = 0.f;
    for (int d=lane; d<512; d+=64) acc += sp[d]*wp[d];
    for (int off=32; off; off>>=1) acc += __shfl_down(acc, off, 64);
    if (lane==0) s[b*512+ic] = acc*0.044194173824159216f + mb[ic]; // 1/sqrt(512)
}

// ---- fused: wsum[oc][ic] = sum_k w^2 ; wpack[tap][oc][ic] = bf16(w) ----
__global__ __launch_bounds__(256) void k_wprep(const float* __restrict__ w,
                                               float* __restrict__ wsum,
                                               u16* __restrict__ wp){
    int idx = blockIdx.x*256 + threadIdx.x; // oc*512+ic, 262144
    const float* p = w + (size_t)idx*9;
    float vv[9]; float a = 0.f;
    #pragma unroll
    for (int t=0;t<9;++t){ float v=p[t]; vv[t]=v; a += v*v; }
    wsum[idx] = a;
    #pragma unroll
    for (int t=0;t<9;++t) wp[(size_t)t*262144 + idx] = f2bf(vv[t]);
}

// ---- dscale[b][oc] = conv_scale * rsqrt(conv_scale^2 * sum_ic s^2*wsum + eps) ----
__global__ __launch_bounds__(256) void k_dscale(const float* __restrict__ s,
                                                const float* __restrict__ wsum,
                                                float* __restrict__ ds){
    int gid = blockIdx.x*4 + (threadIdx.x>>6);
    int lane = threadIdx.x & 63;
    int b = gid>>9, oc = gid & 511;
    const float* sp = s + b*512;
    const float* wp = wsum + (size_t)oc*512;
    float acc=0.f;
    for (int d=lane; d<512; d+=64){ float sv = sp[d]; acc += sv*sv*wp[d]; }
    for (int off=32; off; off>>=1) acc += __shfl_down(acc, off, 64);
    if (lane==0){
        const float cs = 0.014731391274719738f; // 1/sqrt(512*9)
        ds[b*512+oc] = cs * rsqrtf(cs*cs*acc + 1e-8f);
    }
}

// ---- xst[b*1024+px][ic] = bf16(input[b][ic][px] * s[b][ic]) via LDS transpose ----
__global__ __launch_bounds__(256) void k_xst(const float* __restrict__ in,
                                             const float* __restrict__ s,
                                             u16* __restrict__ xst){
    int bx = blockIdx.x;          // b*32 + i
    int b = bx>>5, i = bx&31;
    __shared__ u16 tr[32*520];
    int tid = threadIdx.x;
    int j = tid & 31;
    for (int ic = tid>>5; ic < 512; ic += 8){
        float v = in[((size_t)(b*512+ic)*32 + i)*32 + j] * s[b*512+ic];
        tr[j*520 + ic] = f2bf(v);
    }
    __syncthreads();
    for (int v = tid; v < 2048; v += 256){
        int jj = v>>6, ic8 = (v&63)*8;
        *(uint4*)(xst + (size_t)(b*1024 + i*32 + jj)*512 + ic8) =
            *(const uint4*)(&tr[jj*520 + ic8]);
    }
}

// ---- GEMM: U[m][n] = sum_k wpack[m][k] * xst[n][k], m<4608 ----
// Loop/LDS/epilogue byte-identical to r6 (verified: passed, 0 conflicts,
// VGPR 128 no-spill). r7 changes ONLY the block->tile mapping:
// 2D SUPERTILE L2 mapping. Each XCD owns a static column-slab
// bx in [x*SBX, (x+1)*SBX), SBX = nTN/8, walked in 3-row supertiles:
// concurrent working set = 3 A-panels + SBX B-panels (~2.8 MB, fits 4MB L2);
// the 2MB B-slab stays L2-resident for the whole kernel; A fetched once
// per supertile row. Below-L2 staging demand: 576 MB -> ~55 MB.
__global__ __launch_bounds__(512, 2) void k_gemm(const u16* __restrict__ A,
                                                 const u16* __restrict__ Bx,
                                                 u16* __restrict__ C,
                                                 int Ncols){
    // ---- r7 supertile mapping (bijective; gridDim.x % 8 == 0) ----
    int x = blockIdx.x & 7;           // XCD id (round-robin dispatch)
    int s = blockIdx.x >> 3;          // per-XCD sequence, 0..18*SBX-1
    int SBX = (Ncols >> 8) >> 3;      // n-tiles per XCD slab (8/4/2)
    int st  = s / (3*SBX);            // supertile row (0..5)
    int r   = s - st*(3*SBX);
    int by  = st*3 + r/SBX;           // 18 m-tiles of 256 over M=4608
    int bx  = x*SBX + (r - (r/SBX)*SBX);
    int m0 = by*256, n0 = bx*256;

    int tid = threadIdx.x;
    int lane = tid & 63;
    int w  = tid >> 6;            // 8 waves
    int wm = w >> 2, wn = w & 3;  // 2 x 4 wave grid, wave output 128x64
    int np = lane & 15, qq = lane >> 4;

    __shared__ __align__(16) char smem[131072];
    // buffer q = t&3 at smem + q*32768 : A tile 16KB, B tile at +16KB.

    // ---- staging precompute (inverse swizzle on global source) ----
    int rp1 = tid >> 3, sl1 = tid & 7;
    int v1 = sl1 ^ (rp1 & 7);
    int r1 = rp1*2 + ((v1 >> 2) & 1);
    int g1 = v1 & 3;
    const u16* srcA1 = A  + (size_t)(m0 + r1)*512 + g1*8;
    const u16* srcA2 = srcA1 + (size_t)128*512;    // chunk c+512 -> row+128, same g
    const u16* srcB1 = Bx + (size_t)(n0 + r1)*512 + g1*8;
    const u16* srcB2 = srcB1 + (size_t)128*512;
    int offA1 = (tid & ~63)*8;            // u16 index of wave-uniform LDS base
    int offA2 = offA1 + 4096;             // chunks 512..1023

    // ---- frag read offsets (u16 units) ----
    int rpn = np >> 1;                        // 0..7
    int slA = ((qq + ((np & 1) << 2)) ^ rpn) << 3;   // slot*8 u16
    int pAoff = (wm*64 + rpn)*64 + slA;       // + mf*512
    int pBoff = (wn*32 + rpn)*64 + slA;       // + nf*512, tile base +8192

    floatx4 acc[8][4] = {};

    #define STAGE_A(T) do{ \
        u16* _b = (u16*)smem + ((T)&3)*16384; \
        GLL16(srcA1 + (size_t)(T)*32, _b + offA1); \
        GLL16(srcA2 + (size_t)(T)*32, _b + offA2); \
    }while(0)
    #define STAGE_B(T) do{ \
        u16* _b = (u16*)smem + ((T)&3)*16384; \
        GLL16(srcB1 + (size_t)(T)*32, _b + 8192 + offA1); \
        GLL16(srcB2 + (size_t)(T)*32, _b + 8192 + offA2); \
    }while(0)
    #define CFENCE asm volatile("" ::: "memory")

    short8 af0[8], bf0[4], af1[8], bf1[4];

    // ---- prologue: stage K-tiles 0,1,2; certify tiles 0,1; read frags(0) ----
    STAGE_A(0); STAGE_B(0);
    STAGE_A(1); STAGE_B(1);
    STAGE_A(2); STAGE_B(2);
    asm volatile("s_waitcnt vmcnt(4)" ::: "memory");   // tiles 0 and 1 resident
    __builtin_amdgcn_s_barrier();
    CFENCE;
    {
        const u16* b0 = (const u16*)smem;
        #pragma unroll
        for (int mf = 0; mf < 8; ++mf)
            af0[mf] = *(const short8*)(b0 + pAoff + mf*512);
        #pragma unroll
        for (int nf = 0; nf < 4; ++nf)
            bf0[nf] = *(const short8*)(b0 + 8192 + pBoff + nf*512);
    }

    // body t: barrier | fence | STAGE(t+3) | reads(t+1)->NXT interleaved with
    //         MFMA(t) on CUR | vmcnt certifying t+2 (before next body's barrier)
    #define BODY(T, AC, BC, AN, BN) do{ \
        __builtin_amdgcn_s_barrier(); \
        CFENCE; \
        if ((T) < 13){ STAGE_A((T)+3); STAGE_B((T)+3); } \
        __builtin_amdgcn_s_setprio(1); \
        if ((T) < 15){ \
            const u16* nb = (const u16*)smem + (((T)+1)&3)*16384; \
            _Pragma("unroll") \
            for (int mf = 0; mf < 8; ++mf) \
                AN[mf] = *(const short8*)(nb + pAoff + mf*512); \
            _Pragma("unroll") \
            for (int nf = 0; nf < 4; ++nf) \
                BN[nf] = *(const short8*)(nb + 8192 + pBoff + nf*512); \
        } \
        _Pragma("unroll") \
        for (int mf = 0; mf < 8; ++mf) \
            _Pragma("unroll") \
            for (int nf = 0; nf < 4; ++nf) \
                acc[mf][nf] = __builtin_amdgcn_mfma_f32_16x16x32_bf16( \
                    AC[mf], BC[nf], acc[mf][nf], 0,0,0); \
        __builtin_amdgcn_s_setprio(0); \
        if ((T) < 13)       asm volatile("s_waitcnt vmcnt(4)" ::: "memory"); \
        else if ((T) == 13) asm volatile("s_waitcnt vmcnt(0)" ::: "memory"); \
    }while(0)

    #pragma unroll
    for (int tt = 0; tt < 8; ++tt){
        BODY(2*tt,   af0, bf0, af1, bf1);
        BODY(2*tt+1, af1, bf1, af0, bf0);
    }
    #undef BODY
    #undef STAGE_A
    #undef STAGE_B
    #undef CFENCE

    __syncthreads();   // full drain + fence before LDS reuse by epilogue

    // ---- epilogue: acc -> u32 row-pair packed LDS (rotated) -> coalesced ----
    uint32* Csm32 = (uint32*)smem;        // [128 row-pairs][256 cols] u32
    #pragma unroll
    for (int mf = 0; mf < 8; ++mf){
        #pragma unroll
        for (int nf = 0; nf < 4; ++nf){
            int col = wn*64 + nf*16 + np;
            #pragma unroll
            for (int h = 0; h < 2; ++h){
                int rp = wm*64 + mf*8 + qq*2 + h;
                uint32 v = (uint32)f2bf(acc[mf][nf][2*h]) |
                           ((uint32)f2bf(acc[mf][nf][2*h+1]) << 16);
                Csm32[rp*256 + ((col + rp*8) & 255)] = v;
            }
        }
    }
    __syncthreads();
    #pragma unroll
    for (int i = 0; i < 16; ++i){
        int c = tid + i*512;              // 8192 16B-chunks
        int rp = c >> 6;                  // one rp per wave-instruction
        int pc = (c & 63) * 4;            // physical col base
        uint4 v = *(const uint4*)(&Csm32[rp*256 + pc]);
        int lcol = (pc - rp*8) & 255;     // logical col (4-aligned)
        u16* dst = C + (size_t)(m0 + rp*2)*Ncols + n0 + lcol;
        uint2 e, o;
        e.x = (v.x & 0xffffu) | (v.y << 16);
        e.y = (v.z & 0xffffu) | (v.w << 16);
        o.x = (v.x >> 16)     | (v.y & 0xffff0000u);
        o.y = (v.z >> 16)     | (v.w & 0xffff0000u);
        *(uint2*)(dst) = e;
        *(uint2*)(dst + Ncols) = o;
    }
}

// ---- blur v3: per (b,oc): U taps -> polyphase horizontal rows HR (bf16) -> vertical+out ----
__global__ __launch_bounds__(256) void k_blur2(const u16* __restrict__ U,
                                               const float* __restrict__ ds,
                                               float* __restrict__ out,
                                               int b0, int Ncols){
    int oc = blockIdx.x;
    int bp = blockIdx.y;
    int b  = b0 + bp;
    __shared__ __align__(16) u16 Usm[9*1024];    // 18 KB
    __shared__ __align__(16) u16 HRsm[3*32*64];  // 12 KB
    int tid = threadIdx.x;

    const u16* src0 = U + (size_t)oc*Ncols + (size_t)bp*1024;
    size_t tapstride = (size_t)512 * Ncols;
    #pragma unroll
    for (int it = 0; it < 5; ++it){
        int i = tid + it*256;
        if (i < 1152){
            int tap = i>>7, c8 = i & 127;
            *(uint4*)(&Usm[tap*1024 + c8*8]) =
                *(const uint4*)(src0 + tap*tapstride + c8*8);
        }
    }
    __syncthreads();

    // phase 2: HR rows. task = a*1024 + i*32 + u ; computes X=2u, 2u+1
    #pragma unroll
    for (int it = 0; it < 12; ++it){
        int task = tid + it*256;
        int a = task >> 10, rem = task & 1023;
        int i = rem >> 5, u = rem & 31;
        const u16* base = Usm + a*3072 + i*32;
        float u0  = bf2f(base[u]);
        float u1  = bf2f(base[1024 + u]);
        float u2  = bf2f(base[2048 + u]);
        float u0p = (u < 31) ? bf2f(base[u + 1])        : 0.f;
        float u1m = (u > 0)  ? bf2f(base[1024 + u - 1]) : 0.f;
        float u1p = (u < 31) ? bf2f(base[1024 + u + 1]) : 0.f;
        float u2m = (u > 0)  ? bf2f(base[2048 + u - 1]) : 0.f;
        float HRe = u1m + 3.f*(u0 + u2m + u1) + u0p + u2;
        float HRo = u0 + u2m + 3.f*(u1 + u0p + u2) + u1p;
        uint32 packed = (uint32)f2bf(HRe) | ((uint32)f2bf(HRo) << 16);
        *(uint32*)(&HRsm[(a*32 + i)*64 + 2*u]) = packed;
    }
    __syncthreads();

    // phase 3: vertical 1,3,3,1 over HR rows; float4 out
    float dsc = ds[b*512 + oc] * (1.f/16.f);
    float* op = out + (size_t)(b*512 + oc) * 4096;
    #pragma unroll
    for (int it = 0; it < 4; ++it){
        int task = tid + it*256;      // 1024 tasks: Y (64) x Xq (16)
        int Y = task >> 4, X0 = (task & 15) * 4;
        float o0=0.f,o1=0.f,o2=0.f,o3=0.f;
        int v = Y >> 1;
        #define ACCROW(aa, ii, ww) do{ \
            int _i = (ii); \
            if ((unsigned)_i < 32u){ \
                uint2 rv = *(const uint2*)(&HRsm[((aa)*32 + _i)*64 + X0]); \
                o0 += (ww)*__uint_as_float((rv.x & 0xffffu) << 16); \
                o1 += (ww)*__uint_as_float(rv.x & 0xffff0000u); \
                o2 += (ww)*__uint_as_float((rv.y & 0xffffu) << 16); \
                o3 += (ww)*__uint_as_float(rv.y & 0xffff0000u); \
            } }while(0)
        if ((Y & 1) == 0){
            ACCROW(1, v-1, 1.f);
            ACCROW(0, v,   3.f);
            ACCROW(2, v-1, 3.f);
            ACCROW(1, v,   3.f);
            ACCROW(0, v+1, 1.f);
            ACCROW(2, v,   1.f);
        } else {
            ACCROW(0, v,   1.f);
            ACCROW(2, v-1, 1.f);
            ACCROW(1, v,   3.f);
            ACCROW(0, v+1, 3.f);
            ACCROW(2, v,   3.f);
            ACCROW(1, v+1, 1.f);
        }
        #undef ACCROW
        float4 res = make_float4(dsc*o0, dsc*o1, dsc*o2, dsc*o3);
        *(float4*)(op + Y*64 + X0) = res;
    }
}

extern "C" void kernel_launch(void* const* d_in, const int* in_sizes, int n_in,
                              void* d_out, int out_size, void* d_ws, size_t ws_size,
                              hipStream_t stream){
    const float* input  = (const float*)d_in[0];
    const float* style  = (const float*)d_in[1];
    const float* weight = (const float*)d_in[2];
    const float* mw     = (const float*)d_in[3];
    const float* mb     = (const float*)d_in[4];
    float* out = (float*)d_out;
    char* ws = (char*)d_ws;
    float* s     = (float*)(ws + OFF_S);
    float* ds    = (float*)(ws + OFF_DS);
    float* wsum  = (float*)(ws + OFF_WSUM);
    u16*   wpack = (u16*)(ws + OFF_WPACK);
    u16*   xst   = (u16*)(ws + OFF_XST);
    u16*   U     = (u16*)(ws + OFF_U);

    int NB;
    if      (ws_size >= (size_t)OFF_U + (size_t)4608*16384*2) NB = 16;
    else if (ws_size >= (size_t)OFF_U + (size_t)4608*8192*2)  NB = 8;
    else                                                       NB = 4;
    int npass = 16 / NB;
    int Ncols = NB * 1024;
    int nTilesN = Ncols / 256;

    k_style <<<2048, 256, 0, stream>>>(style, mw, mb, s);
    k_wprep <<<1024, 256, 0, stream>>>(weight, wsum, wpack);
    k_dscale<<<2048, 256, 0, stream>>>(s, wsum, ds);
    k_xst   <<<512,  256, 0, stream>>>(input, s, xst);

    for (int p = 0; p < npass; ++p){
        const u16* xp = xst + (size_t)p * NB * 1024 * 512;
        k_gemm <<<dim3(18*nTilesN), 512, 0, stream>>>(wpack, xp, U, Ncols);
        k_blur2<<<dim3(512, NB),       256, 0, stream>>>(U, ds, out, p*NB, Ncols);
    }
}

// Round 8
// 330.099 us; speedup vs baseline: 1.0296x; 1.0296x over previous
//
#include <hip/hip_runtime.h>
#include <stdint.h>

typedef unsigned int uint32;
typedef unsigned long long u64;
typedef unsigned short u16;
typedef short short8 __attribute__((ext_vector_type(8)));
typedef float floatx4 __attribute__((ext_vector_type(4)));

// ---------------- workspace layout (bytes) ----------------
#define OFF_S      0u           // s[16][512] f32        : 32768
#define OFF_DS     32768u       // dscale[16][512] f32   : 32768
#define OFF_WSUM   65536u       // wsum[512][512] f32    : 1 MB
#define OFF_WPACK  1114112u     // wpack[9][512][512] bf16 (m=tap*512+oc, k=ic): 4.5 MB
#define OFF_XST    5832704u     // xst[16*1024][512] bf16 (n=b*1024+px, k=ic): 16 MB
#define OFF_U      22609920u    // U[4608][NB*1024] bf16 : NB*9.44 MB

__device__ __forceinline__ u16 f2bf(float x){
    uint32 u = __float_as_uint(x);
    uint32 r = (u + 0x7FFFu + ((u>>16)&1u)) >> 16;
    return (u16)r;
}
__device__ __forceinline__ float bf2f(u16 h){
    return __uint_as_float(((uint32)h)<<16);
}

#define GLL16(gp, lp) \
    __builtin_amdgcn_global_load_lds( \
        (const __attribute__((address_space(1))) void*)(gp), \
        (__attribute__((address_space(3))) void*)(lp), 16, 0, 0)

// ---- s[b][ic] = style[b]·mod_weight[ic] * mod_scale + mod_bias[ic] ----
__global__ __launch_bounds__(256) void k_style(const float* __restrict__ style,
                                               const float* __restrict__ mw,
                                               const float* __restrict__ mb,
                                               float* __restrict__ s){
    int gid = blockIdx.x*4 + (threadIdx.x>>6);
    int lane = threadIdx.x & 63;
    int b = gid>>9, ic = gid & 511;
    const float* sp = style + b*512;
    const float* wp = mw + (size_t)ic*512;
    float acc = 0.f;
    for (int d=lane; d<512; d+=64) acc += sp[d]*wp[d];
    for (int off=32; off; off>>=1) acc += __shfl_down(acc, off, 64);
    if (lane==0) s[b*512+ic] = acc*0.044194173824159216f + mb[ic]; // 1/sqrt(512)
}

// ---- fused: wsum[oc][ic] = sum_k w^2 ; wpack[tap][oc][ic] = bf16(w) ----
__global__ __launch_bounds__(256) void k_wprep(const float* __restrict__ w,
                                               float* __restrict__ wsum,
                                               u16* __restrict__ wp){
    int idx = blockIdx.x*256 + threadIdx.x; // oc*512+ic, 262144
    const float* p = w + (size_t)idx*9;
    float vv[9]; float a = 0.f;
    #pragma unroll
    for (int t=0;t<9;++t){ float v=p[t]; vv[t]=v; a += v*v; }
    wsum[idx] = a;
    #pragma unroll
    for (int t=0;t<9;++t) wp[(size_t)t*262144 + idx] = f2bf(vv[t]);
}

// ---- dscale[b][oc] = conv_scale * rsqrt(conv_scale^2 * sum_ic s^2*wsum + eps) ----
__global__ __launch_bounds__(256) void k_dscale(const float* __restrict__ s,
                                                const float* __restrict__ wsum,
                                                float* __restrict__ ds){
    int gid = blockIdx.x*4 + (threadIdx.x>>6);
    int lane = threadIdx.x & 63;
    int b = gid>>9, oc = gid & 511;
    const float* sp = s + b*512;
    const float* wp = wsum + (size_t)oc*512;
    float acc=0.f;
    for (int d=lane; d<512; d+=64){ float sv = sp[d]; acc += sv*sv*wp[d]; }
    for (int off=32; off; off>>=1) acc += __shfl_down(acc, off, 64);
    if (lane==0){
        const float cs = 0.014731391274719738f; // 1/sqrt(512*9)
        ds[b*512+oc] = cs * rsqrtf(cs*cs*acc + 1e-8f);
    }
}

// ---- xst[b*1024+px][ic] = bf16(input[b][ic][px] * s[b][ic]) via LDS transpose ----
__global__ __launch_bounds__(256) void k_xst(const float* __restrict__ in,
                                             const float* __restrict__ s,
                                             u16* __restrict__ xst){
    int bx = blockIdx.x;          // b*32 + i
    int b = bx>>5, i = bx&31;
    __shared__ u16 tr[32*520];
    int tid = threadIdx.x;
    int j = tid & 31;
    for (int ic = tid>>5; ic < 512; ic += 8){
        float v = in[((size_t)(b*512+ic)*32 + i)*32 + j] * s[b*512+ic];
        tr[j*520 + ic] = f2bf(v);
    }
    __syncthreads();
    for (int v = tid; v < 2048; v += 256){
        int jj = v>>6, ic8 = (v&63)*8;
        *(uint4*)(xst + (size_t)(b*1024 + i*32 + jj)*512 + ic8) =
            *(const uint4*)(&tr[jj*520 + ic8]);
    }
}

// ---- GEMM: U[m][n] = sum_k wpack[m][k] * xst[n][k], m<4608 ----
// r8: H4 = phase-lockstep starvation at 1 block/CU. Tile 256x128, BK=32,
// ring-of-2 LDS (48 KiB) -> 2 blocks/CU, 4 waves/SIMD: co-resident block's
// MFMA phase fills this block's stage/drain/prologue/epilogue bubbles
// (m114 mechanism; m97's 874TF had ~3 blocks/CU).
// Inner loop = r3-proven simple drain-per-tile (schedule proven non-binding
// by r2/r3/r6 nulls). Conflict-free row-pair LDS + swizzle as verified r2+.
// Wave tile 64x64 (acc=64 VGPR) so 4 waves/SIMD fit at <=128 VGPR.
__global__ __launch_bounds__(512, 4) void k_gemm(const u16* __restrict__ A,
                                                 const u16* __restrict__ Bx,
                                                 u16* __restrict__ C,
                                                 int Ncols){
    // ---- 2D supertile mapping (bijective; gridDim.x % 8 == 0) ----
    int x = blockIdx.x & 7;           // XCD id
    int s = blockIdx.x >> 3;          // per-XCD sequence
    int SBX = (Ncols >> 7) >> 3;      // n-tiles (128 wide) per XCD slab
    int st  = s / (3*SBX);            // supertile row (0..5)
    int r   = s - st*(3*SBX);
    int by  = st*3 + r/SBX;           // 18 m-tiles of 256
    int bx  = x*SBX + (r - (r/SBX)*SBX);
    int m0 = by*256, n0 = bx*128;

    int tid = threadIdx.x;
    int lane = tid & 63;
    int w  = tid >> 6;            // 8 waves
    int wm = w >> 1, wn = w & 1;  // 4 x 2 wave grid, wave tile 64x64
    int np = lane & 15, qq = lane >> 4;

    __shared__ __align__(16) char smem[49152];
    // buffer q = t&1 at smem + q*24576 : A 256x32 (16KB) + B 128x32 (8KB).

    // ---- staging precompute (inverse swizzle on global source) ----
    // A chunks: c = tid (rows 0..127) and c = tid+512 (rows 128..255);
    // B chunk:  c = tid (rows 0..127). rp=c>>3, slot=c&7,
    // v = slot^(rp&7), row = 2*rp + (v>>2), kgroup g = v&3.
    int rp1 = tid >> 3, sl1 = tid & 7;
    int v1 = sl1 ^ (rp1 & 7);
    int r1 = 2*rp1 + ((v1 >> 2) & 1);
    int g1 = v1 & 3;
    const u16* srcA1 = A  + (size_t)(m0 + r1)*512 + g1*8;
    const u16* srcA2 = srcA1 + (size_t)128*512;    // rows +128, same slot math
    const u16* srcB1 = Bx + (size_t)(n0 + r1)*512 + g1*8;
    int offA1 = (tid & ~63)*8;            // wave-uniform LDS base (u16)
    int offA2 = offA1 + 4096;             // A chunks 512..1023
    int offB  = 8192 + offA1;             // B region base 16KB

    // ---- frag read offsets (u16 units) ----
    int rpn = np >> 1;                               // 0..7
    int slA = ((qq + ((np & 1) << 2)) ^ rpn) << 3;   // slot*8 u16
    int pAoff = (wm*32 + rpn)*64 + slA;   // + mf*512   (wm in 0..3)
    int pBoff = (wn*32 + rpn)*64 + slA;   // + nf*512, B base +8192 (wn in 0..1)

    floatx4 acc[4][4] = {};

    #define STAGE(T) do{ \
        u16* _b = (u16*)smem + ((T)&1)*12288; \
        GLL16(srcA1 + (size_t)(T)*32, _b + offA1); \
        GLL16(srcA2 + (size_t)(T)*32, _b + offA2); \
        GLL16(srcB1 + (size_t)(T)*32, _b + offB); \
    }while(0)
    #define CFENCE asm volatile("" ::: "memory")

    // ---- prologue: stage tile 0, certify, barrier ----
    STAGE(0);
    asm volatile("s_waitcnt vmcnt(0)" ::: "memory");
    __builtin_amdgcn_s_barrier();
    CFENCE;

    #pragma unroll
    for (int t = 0; t < 16; ++t){
        const u16* base = (const u16*)smem + (t & 1)*12288;
        short8 af[4], bfr[4];
        #pragma unroll
        for (int mf = 0; mf < 4; ++mf)
            af[mf] = *(const short8*)(base + pAoff + mf*512);
        #pragma unroll
        for (int nf = 0; nf < 4; ++nf)
            bfr[nf] = *(const short8*)(base + 8192 + pBoff + nf*512);
        if (t < 15) STAGE(t+1);           // other buffer (tile t-1's, reads done)

        __builtin_amdgcn_s_setprio(1);
        #pragma unroll
        for (int mf = 0; mf < 4; ++mf)
            #pragma unroll
            for (int nf = 0; nf < 4; ++nf)
                acc[mf][nf] = __builtin_amdgcn_mfma_f32_16x16x32_bf16(
                    af[mf], bfr[nf], acc[mf][nf], 0,0,0);
        __builtin_amdgcn_s_setprio(0);

        if (t < 15){
            asm volatile("s_waitcnt vmcnt(0)" ::: "memory");  // tile t+1 resident
            __builtin_amdgcn_s_barrier();
            CFENCE;
        }
    }
    #undef STAGE
    #undef CFENCE

    __syncthreads();   // all LDS reads done before epilogue reuse

    // ---- epilogue: chunked (2 x 128 rows) u32 row-pair packed, rotated ----
    uint32* Csm32 = (uint32*)smem;        // [64 row-pairs][128 cols] u32 = 32KB
    #pragma unroll
    for (int ch = 0; ch < 2; ++ch){
        if ((wm >> 1) == ch){             // waves owning rows ch*128..ch*128+127
            #pragma unroll
            for (int mf = 0; mf < 4; ++mf){
                #pragma unroll
                for (int nf = 0; nf < 4; ++nf){
                    int col = wn*64 + nf*16 + np;
                    #pragma unroll
                    for (int h = 0; h < 2; ++h){
                        int rp = (wm&1)*32 + mf*8 + qq*2 + h;   // 0..63
                        uint32 v = (uint32)f2bf(acc[mf][nf][2*h]) |
                                   ((uint32)f2bf(acc[mf][nf][2*h+1]) << 16);
                        Csm32[rp*128 + ((col + rp*8) & 127)] = v;
                    }
                }
            }
        }
        __syncthreads();
        #pragma unroll
        for (int i = 0; i < 4; ++i){
            int c = tid + i*512;          // 2048 16B-chunks
            int rp = c >> 5;              // 0..63
            int pc = (c & 31) * 4;        // physical col base
            uint4 v = *(const uint4*)(&Csm32[rp*128 + pc]);
            int lcol = (pc - rp*8) & 127; // logical col (4-aligned)
            u16* dst = C + (size_t)(m0 + ch*128 + rp*2)*Ncols + n0 + lcol;
            uint2 e, o;
            e.x = (v.x & 0xffffu) | (v.y << 16);
            e.y = (v.z & 0xffffu) | (v.w << 16);
            o.x = (v.x >> 16)     | (v.y & 0xffff0000u);
            o.y = (v.z >> 16)     | (v.w & 0xffff0000u);
            *(uint2*)(dst) = e;
            *(uint2*)(dst + Ncols) = o;
        }
        __syncthreads();
    }
}

// ---- blur v3: per (b,oc): U taps -> polyphase horizontal rows HR (bf16) -> vertical+out ----
__global__ __launch_bounds__(256) void k_blur2(const u16* __restrict__ U,
                                               const float* __restrict__ ds,
                                               float* __restrict__ out,
                                               int b0, int Ncols){
    int oc = blockIdx.x;
    int bp = blockIdx.y;
    int b  = b0 + bp;
    __shared__ __align__(16) u16 Usm[9*1024];    // 18 KB
    __shared__ __align__(16) u16 HRsm[3*32*64];  // 12 KB
    int tid = threadIdx.x;

    const u16* src0 = U + (size_t)oc*Ncols + (size_t)bp*1024;
    size_t tapstride = (size_t)512 * Ncols;
    #pragma unroll
    for (int it = 0; it < 5; ++it){
        int i = tid + it*256;
        if (i < 1152){
            int tap = i>>7, c8 = i & 127;
            *(uint4*)(&Usm[tap*1024 + c8*8]) =
                *(const uint4*)(src0 + tap*tapstride + c8*8);
        }
    }
    __syncthreads();

    // phase 2: HR rows. task = a*1024 + i*32 + u ; computes X=2u, 2u+1
    #pragma unroll
    for (int it = 0; it < 12; ++it){
        int task = tid + it*256;
        int a = task >> 10, rem = task & 1023;
        int i = rem >> 5, u = rem & 31;
        const u16* base = Usm + a*3072 + i*32;
        float u0  = bf2f(base[u]);
        float u1  = bf2f(base[1024 + u]);
        float u2  = bf2f(base[2048 + u]);
        float u0p = (u < 31) ? bf2f(base[u + 1])        : 0.f;
        float u1m = (u > 0)  ? bf2f(base[1024 + u - 1]) : 0.f;
        float u1p = (u < 31) ? bf2f(base[1024 + u + 1]) : 0.f;
        float u2m = (u > 0)  ? bf2f(base[2048 + u - 1]) : 0.f;
        float HRe = u1m + 3.f*(u0 + u2m + u1) + u0p + u2;
        float HRo = u0 + u2m + 3.f*(u1 + u0p + u2) + u1p;
        uint32 packed = (uint32)f2bf(HRe) | ((uint32)f2bf(HRo) << 16);
        *(uint32*)(&HRsm[(a*32 + i)*64 + 2*u]) = packed;
    }
    __syncthreads();

    // phase 3: vertical 1,3,3,1 over HR rows; float4 out
    float dsc = ds[b*512 + oc] * (1.f/16.f);
    float* op = out + (size_t)(b*512 + oc) * 4096;
    #pragma unroll
    for (int it = 0; it < 4; ++it){
        int task = tid + it*256;      // 1024 tasks: Y (64) x Xq (16)
        int Y = task >> 4, X0 = (task & 15) * 4;
        float o0=0.f,o1=0.f,o2=0.f,o3=0.f;
        int v = Y >> 1;
        #define ACCROW(aa, ii, ww) do{ \
            int _i = (ii); \
            if ((unsigned)_i < 32u){ \
                uint2 rv = *(const uint2*)(&HRsm[((aa)*32 + _i)*64 + X0]); \
                o0 += (ww)*__uint_as_float((rv.x & 0xffffu) << 16); \
                o1 += (ww)*__uint_as_float(rv.x & 0xffff0000u); \
                o2 += (ww)*__uint_as_float((rv.y & 0xffffu) << 16); \
                o3 += (ww)*__uint_as_float(rv.y & 0xffff0000u); \
            } }while(0)
        if ((Y & 1) == 0){
            ACCROW(1, v-1, 1.f);
            ACCROW(0, v,   3.f);
            ACCROW(2, v-1, 3.f);
            ACCROW(1, v,   3.f);
            ACCROW(0, v+1, 1.f);
            ACCROW(2, v,   1.f);
        } else {
            ACCROW(0, v,   1.f);
            ACCROW(2, v-1, 1.f);
            ACCROW(1, v,   3.f);
            ACCROW(0, v+1, 3.f);
            ACCROW(2, v,   3.f);
            ACCROW(1, v+1, 1.f);
        }
        #undef ACCROW
        float4 res = make_float4(dsc*o0, dsc*o1, dsc*o2, dsc*o3);
        *(float4*)(op + Y*64 + X0) = res;
    }
}

extern "C" void kernel_launch(void* const* d_in, const int* in_sizes, int n_in,
                              void* d_out, int out_size, void* d_ws, size_t ws_size,
                              hipStream_t stream){
    const float* input  = (const float*)d_in[0];
    const float* style  = (const float*)d_in[1];
    const float* weight = (const float*)d_in[2];
    const float* mw     = (const float*)d_in[3];
    const float* mb     = (const float*)d_in[4];
    float* out = (float*)d_out;
    char* ws = (char*)d_ws;
    float* s     = (float*)(ws + OFF_S);
    float* ds    = (float*)(ws + OFF_DS);
    float* wsum  = (float*)(ws + OFF_WSUM);
    u16*   wpack = (u16*)(ws + OFF_WPACK);
    u16*   xst   = (u16*)(ws + OFF_XST);
    u16*   U     = (u16*)(ws + OFF_U);

    int NB;
    if      (ws_size >= (size_t)OFF_U + (size_t)4608*16384*2) NB = 16;
    else if (ws_size >= (size_t)OFF_U + (size_t)4608*8192*2)  NB = 8;
    else                                                       NB = 4;
    int npass = 16 / NB;
    int Ncols = NB * 1024;

    k_style <<<2048, 256, 0, stream>>>(style, mw, mb, s);
    k_wprep <<<1024, 256, 0, stream>>>(weight, wsum, wpack);
    k_dscale<<<2048, 256, 0, stream>>>(s, wsum, ds);
    k_xst   <<<512,  256, 0, stream>>>(input, s, xst);

    for (int p = 0; p < npass; ++p){
        const u16* xp = xst + (size_t)p * NB * 1024 * 512;
        k_gemm <<<dim3(18 * (Ncols/128)), 512, 0, stream>>>(wpack, xp, U, Ncols);
        k_blur2<<<dim3(512, NB),          256, 0, stream>>>(U, ds, out, p*NB, Ncols);
    }
}